// Round 6
// baseline (1168.463 us; speedup 1.0000x reference)
//
#include <hip/hip_runtime.h>
#include <hip/hip_bf16.h>

// Problem constants
#define B_ 32
#define T_ 600

typedef __attribute__((ext_vector_type(8))) short short8;
typedef __attribute__((ext_vector_type(4))) float f32x4;
typedef __attribute__((ext_vector_type(4))) unsigned short ushort4v;

static __device__ __forceinline__ unsigned short f2bf(float f) {
    unsigned u = __float_as_uint(f);
    u += 0x7FFFu + ((u >> 16) & 1u);
    return (unsigned short)(u >> 16);
}
static __device__ __forceinline__ float bf2f(unsigned short u) {
    return __uint_as_float(((unsigned)u) << 16);
}

// ---------------------------------------------------------------------------
// gemm1: out1h[b,o,t] = bf16( bn(relu(W @ in + bias)) ), in = in0 (+ in1).
// Also zeroes this block's 4096-float SE accumulator.
template<bool HAS_IN2>
__global__ __launch_bounds__(256) void gemm_kernel(
    const float* __restrict__ in0, int s0,
    const float* __restrict__ in1,            // b-stride 614400 (x slice)
    const float* __restrict__ Wg, const float* __restrict__ bias,
    const float* __restrict__ bnp, unsigned short* __restrict__ out,
    float* __restrict__ zbuf4096)
{
    __shared__ unsigned short Al[128][136];   // W[o][c] bf16, +8 pad
    __shared__ unsigned short Bl[64][136];    // in^T [t][c] bf16, +8 pad
    const int tid = threadIdx.x;
    const int b = blockIdx.y;
    const int t0 = blockIdx.x * 64;

    if (zbuf4096 != nullptr) {
        int fid = (b * gridDim.x + blockIdx.x) * 256 + tid;
        if (fid < 4096) zbuf4096[fid] = 0.f;
    }

    // stage A: 128x128 f32 weights -> bf16 LDS
    for (int e = tid; e < 128 * 32; e += 256) {
        int row = e >> 5, c4 = (e & 31) * 4;
        float4 w4 = *(const float4*)&Wg[row * 128 + c4];
        ushort4v u;
        u.x = f2bf(w4.x); u.y = f2bf(w4.y); u.z = f2bf(w4.z); u.w = f2bf(w4.w);
        *(ushort4v*)&Al[row][c4] = u;
    }
    // stage B: in[b, c, t0+t] (+in1) -> Bl[t][c] bf16 (transpose in LDS)
    {
        int t = tid & 63, cb = tid >> 6;
        int gt = t0 + t;
        bool inr = gt < T_;
        const float* p0 = in0 + b * s0 + gt;
        const float* p1 = HAS_IN2 ? (in1 + b * 614400 + gt) : nullptr;
        for (int q = 0; q < 32; q += 8) {
            unsigned short u8[8];
#pragma unroll
            for (int r = 0; r < 8; ++r) {
                int c = cb * 32 + q + r;
                float v = 0.f;
                if (inr) {
                    v = p0[c * T_];
                    if (HAS_IN2) v += p1[c * T_];
                }
                u8[r] = f2bf(v);
            }
            *(short8*)&Bl[t][cb * 32 + q] = *(short8*)u8;
        }
    }
    __syncthreads();

    const int wave = tid >> 6, lane = tid & 63;
    const int mBase = (wave >> 1) * 64, nBase = (wave & 1) * 32;
    const int lr = lane & 15, lq = lane >> 4;

    f32x4 acc[4][2];
#pragma unroll
    for (int mf = 0; mf < 4; ++mf)
#pragma unroll
        for (int nf = 0; nf < 2; ++nf) acc[mf][nf] = {0.f, 0.f, 0.f, 0.f};

#pragma unroll
    for (int kb = 0; kb < 4; ++kb) {
        short8 af[4], bfr[2];
#pragma unroll
        for (int mf = 0; mf < 4; ++mf)
            af[mf] = *(const short8*)&Al[mBase + mf * 16 + lr][kb * 32 + lq * 8];
#pragma unroll
        for (int nf = 0; nf < 2; ++nf)
            bfr[nf] = *(const short8*)&Bl[nBase + nf * 16 + lr][kb * 32 + lq * 8];
#pragma unroll
        for (int mf = 0; mf < 4; ++mf)
#pragma unroll
            for (int nf = 0; nf < 2; ++nf)
                acc[mf][nf] = __builtin_amdgcn_mfma_f32_16x16x32_bf16(
                    af[mf], bfr[nf], acc[mf][nf], 0, 0, 0);
    }

    // epilogue: bias -> relu -> bn -> bf16 store
#pragma unroll
    for (int mf = 0; mf < 4; ++mf) {
#pragma unroll
        for (int i = 0; i < 4; ++i) {
            int o = mBase + mf * 16 + lq * 4 + i;
            float g = bnp[o], be = bnp[128 + o], m = bnp[256 + o], vv = bnp[384 + o];
            float sc = g * rsqrtf(vv + 1e-5f), sh = be - m * sc;
            float bs = bias[o];
#pragma unroll
            for (int nf = 0; nf < 2; ++nf) {
                int t = t0 + nBase + nf * 16 + lr;
                float v = fmaxf(acc[mf][nf][i] + bs, 0.f) * sc + sh;
                if (t < T_) out[(b * 128 + o) * T_ + t] = f2bf(v);
            }
        }
    }
}

// ---------------------------------------------------------------------------
// gemm3 with fused weighted scale-sum staging:
//   B column c<112: sum_s ws_j[s]*chainout[pair0(j)+s][b, c&15, t]  (j=c>>4)
//   B column c>=112: out1h passthrough.
// out3 = bn3(relu(W3 @ B + b3)) (f32) + SE time-sum atomics into ssum.
__global__ __launch_bounds__(256) void gemm3_kernel(
    const unsigned short* __restrict__ chainout,
    const unsigned short* __restrict__ out1h,
    const float* __restrict__ Wg, const float* __restrict__ bias,
    const float* __restrict__ bnp, float* __restrict__ out,
    float* __restrict__ ssum,
    const float* __restrict__ ws0, const float* __restrict__ ws1,
    const float* __restrict__ ws2, const float* __restrict__ ws3,
    const float* __restrict__ ws4, const float* __restrict__ ws5,
    const float* __restrict__ ws6)
{
    __shared__ unsigned short Al[128][136];
    __shared__ unsigned short Bl[64][136];
    __shared__ float wsL[7][8];
    const int tid = threadIdx.x;
    const int b = blockIdx.y;
    const int t0 = blockIdx.x * 64;

    if (tid < 56) {
        int j = tid >> 3, s = tid & 7;
        const float* wp;
        switch (j) {
            case 0: wp = ws0; break; case 1: wp = ws1; break;
            case 2: wp = ws2; break; case 3: wp = ws3; break;
            case 4: wp = ws4; break; case 5: wp = ws5; break;
            default: wp = ws6; break;
        }
        wsL[j][s] = (s < j + 2) ? wp[s] : 0.f;
    }
    __syncthreads();

    // stage A
    for (int e = tid; e < 128 * 32; e += 256) {
        int row = e >> 5, c4 = (e & 31) * 4;
        float4 w4 = *(const float4*)&Wg[row * 128 + c4];
        ushort4v u;
        u.x = f2bf(w4.x); u.y = f2bf(w4.y); u.z = f2bf(w4.z); u.w = f2bf(w4.w);
        *(ushort4v*)&Al[row][c4] = u;
    }
    // stage B with fused wsum (coalesced across lanes: same c, consecutive t)
    {
        int t = tid & 63, cb = tid >> 6;
        int gt = t0 + t;
        bool inr = gt < T_;
        for (int q = 0; q < 32; q += 8) {
            unsigned short u8[8];
#pragma unroll
            for (int r = 0; r < 8; ++r) {
                int c = cb * 32 + q + r;
                float v = 0.f;
                if (inr) {
                    if (c < 112) {
                        int j = c >> 4, i = c & 15;
                        int pair0 = j * (j + 3) / 2;
                        const unsigned short* src = chainout
                            + ((size_t)(pair0 * B_ + b) * 16 + i) * T_ + gt;
                        int nsl = j + 2;
                        float a = 0.f;
                        for (int s = 0; s < nsl; ++s)
                            a += wsL[j][s] * bf2f(src[(size_t)s * B_ * 16 * T_]);
                        v = a;
                    } else {
                        v = bf2f(out1h[((size_t)b * 128 + c) * T_ + gt]);
                    }
                }
                u8[r] = f2bf(v);
            }
            *(short8*)&Bl[t][cb * 32 + q] = *(short8*)u8;
        }
    }
    __syncthreads();

    const int wave = tid >> 6, lane = tid & 63;
    const int mBase = (wave >> 1) * 64, nBase = (wave & 1) * 32;
    const int lr = lane & 15, lq = lane >> 4;

    f32x4 acc[4][2];
#pragma unroll
    for (int mf = 0; mf < 4; ++mf)
#pragma unroll
        for (int nf = 0; nf < 2; ++nf) acc[mf][nf] = {0.f, 0.f, 0.f, 0.f};

#pragma unroll
    for (int kb = 0; kb < 4; ++kb) {
        short8 af[4], bfr[2];
#pragma unroll
        for (int mf = 0; mf < 4; ++mf)
            af[mf] = *(const short8*)&Al[mBase + mf * 16 + lr][kb * 32 + lq * 8];
#pragma unroll
        for (int nf = 0; nf < 2; ++nf)
            bfr[nf] = *(const short8*)&Bl[nBase + nf * 16 + lr][kb * 32 + lq * 8];
#pragma unroll
        for (int mf = 0; mf < 4; ++mf)
#pragma unroll
            for (int nf = 0; nf < 2; ++nf)
                acc[mf][nf] = __builtin_amdgcn_mfma_f32_16x16x32_bf16(
                    af[mf], bfr[nf], acc[mf][nf], 0, 0, 0);
    }

#pragma unroll
    for (int mf = 0; mf < 4; ++mf) {
#pragma unroll
        for (int i = 0; i < 4; ++i) {
            int o = mBase + mf * 16 + lq * 4 + i;
            float g = bnp[o], be = bnp[128 + o], m = bnp[256 + o], vv = bnp[384 + o];
            float sc = g * rsqrtf(vv + 1e-5f), sh = be - m * sc;
            float bs = bias[o];
            float psum = 0.f;
#pragma unroll
            for (int nf = 0; nf < 2; ++nf) {
                int t = t0 + nBase + nf * 16 + lr;
                float v = fmaxf(acc[mf][nf][i] + bs, 0.f) * sc + sh;
                if (t < T_) { out[(b * 128 + o) * T_ + t] = v; psum += v; }
            }
            psum += __shfl_xor(psum, 1);
            psum += __shfl_xor(psum, 2);
            psum += __shfl_xor(psum, 4);
            psum += __shfl_xor(psum, 8);
            if (lr == 0) atomicAdd(&ssum[b * 128 + o], psum);
        }
    }
}

// ---------------------------------------------------------------------------
// Inner Res2 chain via MFMA, TI=50 for 9x parallelism (3072 wgs).
// State bf16 in LDS [row=t+2][16ch], row stride 24 ushorts (48B).
constexpr int TI = 50;      // 600 = 12 * 50 (exact)
constexpr int NROW = 84;    // max read row t+4 <= 83 (X<=78)
constexpr int RS = 24;      // row stride in ushorts (48 bytes)

__global__ __launch_bounds__(128, 3) void inner_kernel(
    const unsigned short* __restrict__ out1,
    unsigned short* __restrict__ chainout,
    const float* __restrict__ cwB, const float* __restrict__ cbB,
    const float* __restrict__ ibnB)
{
    __shared__ __attribute__((aligned(16))) unsigned short st[2][NROW][RS];
    __shared__ __attribute__((aligned(16))) unsigned short wL1[7 * 16 * 32];
    __shared__ __attribute__((aligned(16))) unsigned short wL2[7 * 16 * 16];
    __shared__ __attribute__((aligned(16))) unsigned short zb[16];
    __shared__ __attribute__((aligned(16))) float pL[7 * 16][4];

    const int tid = threadIdx.x;
    const int tile = blockIdx.x;   // 0..11
    const int c = blockIdx.y;      // chain 0..7
    const int b = blockIdx.z;

    const int j0 = (c <= 1) ? 0 : (c - 1);
    const int nconv = 7 - j0;
    const int halo = 2 * nconv;
    const int X = TI + 2 * halo;   // <= 78
    const int ch0 = (c == 0) ? 112 : 16 * (c - 1);
    const int t0g = tile * TI - halo;

    // zero both state buffers; zero block for MFMA#2 upper K half
    for (int e = tid; e < 2 * NROW * RS / 4; e += 128)
        ((ushort4v*)st)[e] = ushort4v{0, 0, 0, 0};
    if (tid < 16) zb[tid] = 0;

    // stage conv weights (bf16): wL1[k][o][tap*16+i] taps 0,1; wL2[k][o][i] tap 2
    for (int e = tid; e < nconv * 512; e += 128) {
        int k = e >> 9, rem = e & 511, o = rem >> 5, col = rem & 31;
        int tap = col >> 4, i = col & 15;
        wL1[e] = f2bf(cwB[((j0 + k) * 16 + o) * 48 + i * 3 + tap]);
    }
    for (int e = tid; e < nconv * 256; e += 128) {
        int k = e >> 8, rem = e & 255, o = rem >> 4, i = rem & 15;
        wL2[e] = f2bf(cwB[((j0 + k) * 16 + o) * 48 + i * 3 + 2]);
    }
    // per-(step, out-ch) params: {bias, bn_scale, bn_shift, 0}
    for (int e = tid; e < nconv * 16; e += 128) {
        int k = e >> 4, o = e & 15, j = j0 + k;
        float g = ibnB[(j * 4 + 0) * 16 + o], bb = ibnB[(j * 4 + 1) * 16 + o];
        float m = ibnB[(j * 4 + 2) * 16 + o], v = ibnB[(j * 4 + 3) * 16 + o];
        float sc = g * rsqrtf(v + 1e-5f);
        pL[e][0] = cbB[j * 16 + o];
        pL[e][1] = sc;
        pL[e][2] = bb - m * sc;
        pL[e][3] = 0.f;
    }
    __syncthreads();   // zero-init visible before state staging writes

    // stage initial state rows [2, X+2)
    {
        const int i = tid >> 3, ph = tid & 7;
        const unsigned short* src = out1 + (size_t)(b * 128 + ch0 + i) * T_;
        for (int t = ph; t < X; t += 8) {
            int g = t0g + t;
            st[0][t + 2][i] = ((unsigned)g < (unsigned)T_) ? src[g] : (unsigned short)0;
        }
    }
    __syncthreads();

    const int lane = tid & 63, wave = tid >> 6;
    const int lt = lane & 15, q = lane >> 4;
    const int i0 = (q & 1) * 8;
    const int roff1 = (q < 2) ? 0 : 2;   // MFMA#1: taps at rows t / t+2

    int cur = 0;
    for (int k = 0; k < nconv; ++k) {
        const int olo = 2 * k + 2, ohi = X - 2 * k - 2;
        const int thi = (ohi + 15) >> 4;   // tiles to compute
        const int nxt = cur ^ 1;

        short8 A1 = *(const short8*)&wL1[(k * 16 + lt) * 32 + q * 8];
        short8 A2 = (q < 2)
            ? *(const short8*)&wL2[(k * 16 + lt) * 16 + q * 8]
            : *(const short8*)&zb[i0];
        float4 pp[4];
#pragma unroll
        for (int r = 0; r < 4; ++r)
            pp[r] = *(const float4*)&pL[k * 16 + 4 * q + r][0];

        for (int tt = wave; tt < thi; tt += 2) {
            const int t = tt * 16 + lt;
            f32x4 acc = {0.f, 0.f, 0.f, 0.f};
            short8 B1 = *(const short8*)&st[cur][t + roff1][i0];
            acc = __builtin_amdgcn_mfma_f32_16x16x32_bf16(A1, B1, acc, 0, 0, 0);
            short8 B2 = *(const short8*)&st[cur][t + 4][i0];
            acc = __builtin_amdgcn_mfma_f32_16x16x32_bf16(A2, B2, acc, 0, 0, 0);

            const int g = t0g + t;
            const bool ok = (t >= olo) && (t < ohi) && ((unsigned)g < (unsigned)T_);
            ushort4v o4;
#pragma unroll
            for (int r = 0; r < 4; ++r) {
                float v = fmaxf(acc[r] + pp[r].x, 0.f) * pp[r].y + pp[r].z;
                unsigned short h = f2bf(v);
                o4[r] = ok ? h : (unsigned short)0;
            }
            *(ushort4v*)&st[nxt][t + 2][4 * q] = o4;
        }
        __syncthreads();

        // store central TI columns of new state to chainout (bf16)
        {
            const int j = j0 + k;
            const int pair = j * (j + 3) / 2 + c;
            unsigned short* dst = chainout + ((size_t)(pair * B_ + b) * 16) * T_
                                + tile * TI;
            const int i = tid >> 3, ph = tid & 7;
            for (int t2 = ph; t2 < TI; t2 += 8)
                dst[i * T_ + t2] = st[nxt][halo + t2 + 2][i];
        }
        cur = nxt;
    }
}

// ---------------------------------------------------------------------------
// Elementwise tail with fused SE excitation:
//   s2 = sigmoid(W2 relu(W1 (ssum/T) + b1) + b2)   (computed per-wg)
//   y = out3*s2 + residual; sp = obn(relu(y)); store sp;
//   pooled[b, chOff+c] = mean_t relu(fbn(sp)).
template<bool HAS_R2>
__global__ __launch_bounds__(256) void fuse_kernel(
    const float* __restrict__ out3, const float* __restrict__ ssum,
    const float* __restrict__ w1se, const float* __restrict__ b1se,
    const float* __restrict__ w2se, const float* __restrict__ b2se,
    const float* __restrict__ res0, int r0s,
    const float* __restrict__ res1,
    const float* __restrict__ obnp, const float* __restrict__ fbnp, int chOff,
    float* __restrict__ spOut, float* __restrict__ pooled)
{
    __shared__ float sL[128], red[128], hL[16];
    const int tid = threadIdx.x;
    const int row = blockIdx.x * 4 + (tid >> 6);
    const int lane = tid & 63;
    const int b = row >> 7, c = row & 127;   // b uniform per wg (4 rows/wg)

    // SE MLP (redundant per wg; ~2K FMA)
    if (tid < 128) sL[tid] = ssum[b * 128 + tid] * (1.f / 600.f);
    __syncthreads();
    if (tid < 128) {
        int h = tid >> 3, part = tid & 7;
        float a = 0.f;
        const float* wrow = w1se + h * 128 + part * 16;
#pragma unroll
        for (int k = 0; k < 16; ++k) a += wrow[k] * sL[part * 16 + k];
        red[tid] = a;
    }
    __syncthreads();
    if (tid < 16) {
        float a = b1se[tid];
#pragma unroll
        for (int p = 0; p < 8; ++p) a += red[tid * 8 + p];
        hL[tid] = fmaxf(a, 0.f);
    }
    __syncthreads();
    float a2 = b2se[c];
#pragma unroll
    for (int qq = 0; qq < 16; ++qq) a2 += w2se[c * 16 + qq] * hL[qq];
    const float s2v = 1.f / (1.f + expf(-a2));

    float g = obnp[c], bb = obnp[128 + c], m = obnp[256 + c], v = obnp[384 + c];
    float osc = g * rsqrtf(v + 1e-5f), osh = bb - m * osc;
    int fc = chOff + c;
    float fg = fbnp[fc], fb2 = fbnp[1024 + fc], fm = fbnp[2048 + fc], fv = fbnp[3072 + fc];
    float fsc = fg * rsqrtf(fv + 1e-5f), fsh = fb2 - fm * fsc;
    int base = (b * 128 + c) * T_;
    float psum = 0.f;
    for (int t = lane; t < T_; t += 64) {
        float o3 = out3[base + t];
        float r = res0[b * r0s + c * T_ + t];
        if (HAS_R2) r += res1[b * 614400 + c * T_ + t];
        float fin = o3 * s2v + r;
        float sp = fmaxf(fin, 0.f) * osc + osh;
        spOut[base + t] = sp;
        psum += fmaxf(sp * fsc + fsh, 0.f);
    }
    for (int mo = 32; mo > 0; mo >>= 1) psum += __shfl_xor(psum, mo);
    if (lane == 0) pooled[b * 1024 + fc] = psum * (1.f / 600.f);
}

// pooled tail for x channels 896..1023
__global__ __launch_bounds__(256) void pooledx_kernel(
    const float* __restrict__ x, const float* __restrict__ fbnp,
    float* __restrict__ pooled)
{
    const int tid = threadIdx.x;
    const int row = blockIdx.x * 4 + (tid >> 6);
    const int lane = tid & 63;
    const int b = row >> 7, c = row & 127;
    int fc = 896 + c;
    float fg = fbnp[fc], fb2 = fbnp[1024 + fc], fm = fbnp[2048 + fc], fv = fbnp[3072 + fc];
    float fsc = fg * rsqrtf(fv + 1e-5f), fsh = fb2 - fm * fsc;
    int base = (b * 1024 + fc) * T_;
    float psum = 0.f;
    for (int t = lane; t < T_; t += 64)
        psum += fmaxf(x[base + t] * fsc + fsh, 0.f);
    for (int mo = 32; mo > 0; mo >>= 1) psum += __shfl_xor(psum, mo);
    if (lane == 0) pooled[b * 1024 + fc] = psum * (1.f / 600.f);
}

// final classifier
__global__ __launch_bounds__(256) void logits_kernel(
    const float* __restrict__ pooled, const float* __restrict__ fcw,
    const float* __restrict__ fcb, float* __restrict__ outp)
{
    __shared__ float red[256];
    const int tid = threadIdx.x;
    const int item = tid & 63, part = tid >> 6;
    const int b = item >> 1, cls = item & 1;
    float a = 0.f;
    for (int c = part * 256; c < part * 256 + 256; ++c)
        a += pooled[b * 1024 + c] * fcw[cls * 1024 + c];
    red[tid] = a;
    __syncthreads();
    if (tid < 64)
        outp[b * 2 + cls] = red[tid] + red[tid + 64] + red[tid + 128] + red[tid + 192] + fcb[cls];
}

// ---------------------------------------------------------------------------
extern "C" void kernel_launch(void* const* d_in, const int* in_sizes, int n_in,
                              void* d_out, int out_size, void* d_ws, size_t ws_size,
                              hipStream_t stream) {
    const float* x    = (const float*)d_in[0];
    const float* w1   = (const float*)d_in[1];
    const float* b1   = (const float*)d_in[2];
    const float* bn1  = (const float*)d_in[3];
    const float* cw   = (const float*)d_in[4];
    const float* cb   = (const float*)d_in[5];
    const float* ibn  = (const float*)d_in[6];
    const float* w3   = (const float*)d_in[7];
    const float* b3   = (const float*)d_in[8];
    const float* bn3  = (const float*)d_in[9];
    const float* se1w = (const float*)d_in[10];
    const float* se1b = (const float*)d_in[11];
    const float* se2w = (const float*)d_in[12];
    const float* se2b = (const float*)d_in[13];
    const float* obn  = (const float*)d_in[14];
    const float* fbn  = (const float*)d_in[15];
    const float* fcw  = (const float*)d_in[16];
    const float* fcb  = (const float*)d_in[17];
    const float* wsp[7] = {(const float*)d_in[18], (const float*)d_in[19],
                           (const float*)d_in[20], (const float*)d_in[21],
                           (const float*)d_in[22], (const float*)d_in[23],
                           (const float*)d_in[24]};

    float* ws = (float*)d_ws;
    const int NT = 128 * T_ * B_;          // 2,457,600 per (B,128,T) tensor
    unsigned short* out1h = (unsigned short*)ws;   // bf16, in NT-float region
    float* out3   = ws + NT;
    float* spA    = out3 + NT;
    float* spB    = spA + NT;
    float* sbuf   = spB + NT;              // 7*4096
    float* pooled = sbuf + 7 * 4096;       // 32768
    unsigned short* chainout = (unsigned short*)(pooled + 32768); // 35*32*9600

    pooledx_kernel<<<1024, 256, 0, stream>>>(x, fbn, pooled);

    dim3 gGrid(10, B_);        // ceil(600/64) x B
    dim3 iGrid(12, 8, B_);     // t-tiles x chains x B

    float* spBufs[2] = {spA, spB};
    for (int i = 0; i < 7; ++i) {
        float* spOut = spBufs[i & 1];
        const float* spIn = spBufs[(i & 1) ^ 1];

        if (i == 0)
            gemm_kernel<false><<<gGrid, 256, 0, stream>>>(
                x, 614400, nullptr, w1, b1, bn1, out1h, sbuf + i * 4096);
        else
            gemm_kernel<true><<<gGrid, 256, 0, stream>>>(
                spIn, 76800, x + i * 76800,
                w1 + i * 16384, b1 + i * 128, bn1 + i * 512, out1h,
                sbuf + i * 4096);

        inner_kernel<<<iGrid, 128, 0, stream>>>(
            out1h, chainout, cw + i * 5376, cb + i * 112, ibn + i * 448);

        gemm3_kernel<<<gGrid, 256, 0, stream>>>(
            chainout, out1h,
            w3 + i * 16384, b3 + i * 128, bn3 + i * 512, out3, sbuf + i * 4096,
            wsp[0] + 2 * i, wsp[1] + 3 * i, wsp[2] + 4 * i, wsp[3] + 5 * i,
            wsp[4] + 6 * i, wsp[5] + 7 * i, wsp[6] + 8 * i);

        if (i == 0)
            fuse_kernel<false><<<1024, 256, 0, stream>>>(
                out3, sbuf + i * 4096, se1w, se1b, se2w, se2b,
                x, 614400, nullptr, obn, fbn, 0, spOut, pooled);
        else
            fuse_kernel<true><<<1024, 256, 0, stream>>>(
                out3, sbuf + i * 4096,
                se1w + i * 2048, se1b + i * 16, se2w + i * 2048, se2b + i * 128,
                spIn, 76800, x + i * 76800,
                obn + i * 512, fbn, i * 128, spOut, pooled);
    }

    logits_kernel<<<1, 256, 0, stream>>>(pooled, fcw, fcb, (float*)d_out);
}

// Round 8
// 891.867 us; speedup vs baseline: 1.3101x; 1.3101x over previous
//
#include <hip/hip_runtime.h>
#include <hip/hip_bf16.h>

// Problem constants
#define B_ 32
#define T_ 600

typedef __attribute__((ext_vector_type(8))) short short8;
typedef __attribute__((ext_vector_type(4))) float f32x4;
typedef __attribute__((ext_vector_type(4))) unsigned short ushort4v;

static __device__ __forceinline__ unsigned short f2bf(float f) {
    unsigned u = __float_as_uint(f);
    u += 0x7FFFu + ((u >> 16) & 1u);
    return (unsigned short)(u >> 16);
}
static __device__ __forceinline__ float bf2f(unsigned short u) {
    return __uint_as_float(((unsigned)u) << 16);
}

// ---------------------------------------------------------------------------
// gemm1: out1h[b,o,t] = bf16( bn(relu(W @ in + bias)) ), in = in0 (+ in1).
// Also zeroes this block's 4096-float SE accumulator.
template<bool HAS_IN2>
__global__ __launch_bounds__(256) void gemm_kernel(
    const float* __restrict__ in0, int s0,
    const float* __restrict__ in1,            // b-stride 614400 (x slice)
    const float* __restrict__ Wg, const float* __restrict__ bias,
    const float* __restrict__ bnp, unsigned short* __restrict__ out,
    float* __restrict__ zbuf4096)
{
    __shared__ unsigned short Al[128][136];   // W[o][c] bf16, +8 pad
    __shared__ unsigned short Bl[64][136];    // in^T [t][c] bf16, +8 pad
    const int tid = threadIdx.x;
    const int b = blockIdx.y;
    const int t0 = blockIdx.x * 64;

    if (zbuf4096 != nullptr) {
        int fid = (b * gridDim.x + blockIdx.x) * 256 + tid;
        if (fid < 4096) zbuf4096[fid] = 0.f;
    }

    // stage A: 128x128 f32 weights -> bf16 LDS
    for (int e = tid; e < 128 * 32; e += 256) {
        int row = e >> 5, c4 = (e & 31) * 4;
        float4 w4 = *(const float4*)&Wg[row * 128 + c4];
        ushort4v u;
        u.x = f2bf(w4.x); u.y = f2bf(w4.y); u.z = f2bf(w4.z); u.w = f2bf(w4.w);
        *(ushort4v*)&Al[row][c4] = u;
    }
    // stage B: in[b, c, t0+t] (+in1) -> Bl[t][c] bf16 (transpose in LDS)
    {
        int t = tid & 63, cb = tid >> 6;
        int gt = t0 + t;
        bool inr = gt < T_;
        const float* p0 = in0 + b * s0 + gt;
        const float* p1 = HAS_IN2 ? (in1 + b * 614400 + gt) : nullptr;
        for (int q = 0; q < 32; q += 8) {
            unsigned short u8[8];
#pragma unroll
            for (int r = 0; r < 8; ++r) {
                int c = cb * 32 + q + r;
                float v = 0.f;
                if (inr) {
                    v = p0[c * T_];
                    if (HAS_IN2) v += p1[c * T_];
                }
                u8[r] = f2bf(v);
            }
            *(short8*)&Bl[t][cb * 32 + q] = *(short8*)u8;
        }
    }
    __syncthreads();

    const int wave = tid >> 6, lane = tid & 63;
    const int mBase = (wave >> 1) * 64, nBase = (wave & 1) * 32;
    const int lr = lane & 15, lq = lane >> 4;

    f32x4 acc[4][2];
#pragma unroll
    for (int mf = 0; mf < 4; ++mf)
#pragma unroll
        for (int nf = 0; nf < 2; ++nf) acc[mf][nf] = {0.f, 0.f, 0.f, 0.f};

#pragma unroll
    for (int kb = 0; kb < 4; ++kb) {
        short8 af[4], bfr[2];
#pragma unroll
        for (int mf = 0; mf < 4; ++mf)
            af[mf] = *(const short8*)&Al[mBase + mf * 16 + lr][kb * 32 + lq * 8];
#pragma unroll
        for (int nf = 0; nf < 2; ++nf)
            bfr[nf] = *(const short8*)&Bl[nBase + nf * 16 + lr][kb * 32 + lq * 8];
#pragma unroll
        for (int mf = 0; mf < 4; ++mf)
#pragma unroll
            for (int nf = 0; nf < 2; ++nf)
                acc[mf][nf] = __builtin_amdgcn_mfma_f32_16x16x32_bf16(
                    af[mf], bfr[nf], acc[mf][nf], 0, 0, 0);
    }

    // epilogue: bias -> relu -> bn -> bf16 store
#pragma unroll
    for (int mf = 0; mf < 4; ++mf) {
#pragma unroll
        for (int i = 0; i < 4; ++i) {
            int o = mBase + mf * 16 + lq * 4 + i;
            float g = bnp[o], be = bnp[128 + o], m = bnp[256 + o], vv = bnp[384 + o];
            float sc = g * rsqrtf(vv + 1e-5f), sh = be - m * sc;
            float bs = bias[o];
#pragma unroll
            for (int nf = 0; nf < 2; ++nf) {
                int t = t0 + nBase + nf * 16 + lr;
                float v = fmaxf(acc[mf][nf][i] + bs, 0.f) * sc + sh;
                if (t < T_) out[(b * 128 + o) * T_ + t] = f2bf(v);
            }
        }
    }
}

// ---------------------------------------------------------------------------
// gemm3 with fused weighted scale-sum, vectorized via LDS transpose bounce:
//  Phase A: coalesced short8 loads of chainout/out1h along t; f32 weighted
//           sums -> W[c][64] in LDS (W shares storage with Al).
//  Phase B: W -> Bl[t][c] bf16 (LDS->LDS transpose, conflict-free).
//  Phase C: stage Al (W region dead). Then MFMA + epilogue + SE time-sums.
__global__ __launch_bounds__(256) void gemm3_kernel(
    const unsigned short* __restrict__ chainout,
    const unsigned short* __restrict__ out1h,
    const float* __restrict__ Wg, const float* __restrict__ bias,
    const float* __restrict__ bnp, float* __restrict__ out,
    float* __restrict__ ssum,
    const float* __restrict__ ws0, const float* __restrict__ ws1,
    const float* __restrict__ ws2, const float* __restrict__ ws3,
    const float* __restrict__ ws4, const float* __restrict__ ws5,
    const float* __restrict__ ws6)
{
    __shared__ __attribute__((aligned(16))) char AW[128 * 136 * 2]; // Al | W
    __shared__ __attribute__((aligned(16))) unsigned short Bl[64][136];
    __shared__ float wsL[7][8];
    unsigned short (*Al)[136] = (unsigned short (*)[136])AW;
    float (*W)[64] = (float (*)[64])AW;

    const int tid = threadIdx.x;
    const int b = blockIdx.y;
    const int t0 = blockIdx.x * 64;

    if (tid < 56) {
        int j = tid >> 3, s = tid & 7;
        const float* wp;
        switch (j) {
            case 0: wp = ws0; break; case 1: wp = ws1; break;
            case 2: wp = ws2; break; case 3: wp = ws3; break;
            case 4: wp = ws4; break; case 5: wp = ws5; break;
            default: wp = ws6; break;
        }
        wsL[j][s] = (s < j + 2) ? wp[s] : 0.f;
    }
    __syncthreads();

    // Phase A: vectorized global loads + weighted sum -> W[c][t] (f32)
#pragma unroll
    for (int it = 0; it < 4; ++it) {
        int e = it * 256 + tid;          // 0..1023
        int c = e >> 3, tv = e & 7;
        int gt0 = t0 + tv * 8;
        float acc[8] = {0.f, 0.f, 0.f, 0.f, 0.f, 0.f, 0.f, 0.f};
        if (gt0 < T_) {
            if (c < 112) {
                int j = c >> 4, i = c & 15;
                int pair0 = j * (j + 3) / 2, nsl = j + 2;
                const unsigned short* src = chainout
                    + ((size_t)(pair0 * B_ + b) * 16 + i) * T_ + gt0;
                for (int s = 0; s < nsl; ++s) {
                    short8 v = *(const short8*)(src + (size_t)s * B_ * 16 * T_);
                    float w = wsL[j][s];
#pragma unroll
                    for (int d = 0; d < 8; ++d)
                        acc[d] += w * bf2f((unsigned short)v[d]);
                }
            } else {
                short8 v = *(const short8*)(out1h + ((size_t)b * 128 + c) * T_ + gt0);
#pragma unroll
                for (int d = 0; d < 8; ++d)
                    acc[d] = bf2f((unsigned short)v[d]);
            }
        }
        *(f32x4*)&W[c][tv * 8]     = {acc[0], acc[1], acc[2], acc[3]};
        *(f32x4*)&W[c][tv * 8 + 4] = {acc[4], acc[5], acc[6], acc[7]};
    }
    __syncthreads();

    // Phase B: W[c][t] -> Bl[t][c] bf16
    {
        int t = tid & 63, cb = tid >> 6;
        for (int q = 0; q < 32; q += 8) {
            unsigned short u8[8];
#pragma unroll
            for (int r = 0; r < 8; ++r)
                u8[r] = f2bf(W[cb * 32 + q + r][t]);
            *(short8*)&Bl[t][cb * 32 + q] = *(short8*)u8;
        }
    }
    __syncthreads();

    // Phase C: stage Al (overwrites dead W region)
    for (int e = tid; e < 128 * 32; e += 256) {
        int row = e >> 5, c4 = (e & 31) * 4;
        float4 w4 = *(const float4*)&Wg[row * 128 + c4];
        ushort4v u;
        u.x = f2bf(w4.x); u.y = f2bf(w4.y); u.z = f2bf(w4.z); u.w = f2bf(w4.w);
        *(ushort4v*)&Al[row][c4] = u;
    }
    __syncthreads();

    const int wave = tid >> 6, lane = tid & 63;
    const int mBase = (wave >> 1) * 64, nBase = (wave & 1) * 32;
    const int lr = lane & 15, lq = lane >> 4;

    f32x4 acc[4][2];
#pragma unroll
    for (int mf = 0; mf < 4; ++mf)
#pragma unroll
        for (int nf = 0; nf < 2; ++nf) acc[mf][nf] = {0.f, 0.f, 0.f, 0.f};

#pragma unroll
    for (int kb = 0; kb < 4; ++kb) {
        short8 af[4], bfr[2];
#pragma unroll
        for (int mf = 0; mf < 4; ++mf)
            af[mf] = *(const short8*)&Al[mBase + mf * 16 + lr][kb * 32 + lq * 8];
#pragma unroll
        for (int nf = 0; nf < 2; ++nf)
            bfr[nf] = *(const short8*)&Bl[nBase + nf * 16 + lr][kb * 32 + lq * 8];
#pragma unroll
        for (int mf = 0; mf < 4; ++mf)
#pragma unroll
            for (int nf = 0; nf < 2; ++nf)
                acc[mf][nf] = __builtin_amdgcn_mfma_f32_16x16x32_bf16(
                    af[mf], bfr[nf], acc[mf][nf], 0, 0, 0);
    }

#pragma unroll
    for (int mf = 0; mf < 4; ++mf) {
#pragma unroll
        for (int i = 0; i < 4; ++i) {
            int o = mBase + mf * 16 + lq * 4 + i;
            float g = bnp[o], be = bnp[128 + o], m = bnp[256 + o], vv = bnp[384 + o];
            float sc = g * rsqrtf(vv + 1e-5f), sh = be - m * sc;
            float bs = bias[o];
            float psum = 0.f;
#pragma unroll
            for (int nf = 0; nf < 2; ++nf) {
                int t = t0 + nBase + nf * 16 + lr;
                float v = fmaxf(acc[mf][nf][i] + bs, 0.f) * sc + sh;
                if (t < T_) { out[(b * 128 + o) * T_ + t] = v; psum += v; }
            }
            psum += __shfl_xor(psum, 1);
            psum += __shfl_xor(psum, 2);
            psum += __shfl_xor(psum, 4);
            psum += __shfl_xor(psum, 8);
            if (lr == 0) atomicAdd(&ssum[b * 128 + o], psum);
        }
    }
}

// ---------------------------------------------------------------------------
// Inner Res2 chain via MFMA, TI=50 (12 t-tiles x 8 chains x 32 b = 3072 wgs).
// State bf16 in LDS [row=t+2][16ch], row stride 24 ushorts (48B).
constexpr int TI = 50;      // 600 = 12 * 50 (exact)
constexpr int NROW = 84;    // max read row t+4 <= 83 (X<=78)
constexpr int RS = 24;      // row stride in ushorts (48 bytes)

__global__ __launch_bounds__(128, 3) void inner_kernel(
    const unsigned short* __restrict__ out1,
    unsigned short* __restrict__ chainout,
    const float* __restrict__ cwB, const float* __restrict__ cbB,
    const float* __restrict__ ibnB)
{
    __shared__ __attribute__((aligned(16))) unsigned short st[2][NROW][RS];
    __shared__ __attribute__((aligned(16))) unsigned short wL1[7 * 16 * 32];
    __shared__ __attribute__((aligned(16))) unsigned short wL2[7 * 16 * 16];
    __shared__ __attribute__((aligned(16))) unsigned short zb[16];
    __shared__ __attribute__((aligned(16))) float pL[7 * 16][4];

    const int tid = threadIdx.x;
    const int tile = blockIdx.x;   // 0..11
    const int c = blockIdx.y;      // chain 0..7
    const int b = blockIdx.z;

    const int j0 = (c <= 1) ? 0 : (c - 1);
    const int nconv = 7 - j0;
    const int halo = 2 * nconv;
    const int X = TI + 2 * halo;   // <= 78
    const int ch0 = (c == 0) ? 112 : 16 * (c - 1);
    const int t0g = tile * TI - halo;

    // zero both state buffers; zero block for MFMA#2 upper K half
    for (int e = tid; e < 2 * NROW * RS / 4; e += 128)
        ((ushort4v*)st)[e] = ushort4v{0, 0, 0, 0};
    if (tid < 16) zb[tid] = 0;

    // stage conv weights (bf16): wL1[k][o][tap*16+i] taps 0,1; wL2[k][o][i] tap 2
    for (int e = tid; e < nconv * 512; e += 128) {
        int k = e >> 9, rem = e & 511, o = rem >> 5, col = rem & 31;
        int tap = col >> 4, i = col & 15;
        wL1[e] = f2bf(cwB[((j0 + k) * 16 + o) * 48 + i * 3 + tap]);
    }
    for (int e = tid; e < nconv * 256; e += 128) {
        int k = e >> 8, rem = e & 255, o = rem >> 4, i = rem & 15;
        wL2[e] = f2bf(cwB[((j0 + k) * 16 + o) * 48 + i * 3 + 2]);
    }
    // per-(step, out-ch) params: {bias, bn_scale, bn_shift, 0}
    for (int e = tid; e < nconv * 16; e += 128) {
        int k = e >> 4, o = e & 15, j = j0 + k;
        float g = ibnB[(j * 4 + 0) * 16 + o], bb = ibnB[(j * 4 + 1) * 16 + o];
        float m = ibnB[(j * 4 + 2) * 16 + o], v = ibnB[(j * 4 + 3) * 16 + o];
        float sc = g * rsqrtf(v + 1e-5f);
        pL[e][0] = cbB[j * 16 + o];
        pL[e][1] = sc;
        pL[e][2] = bb - m * sc;
        pL[e][3] = 0.f;
    }
    __syncthreads();   // zero-init visible before state staging writes

    // stage initial state rows [2, X+2)
    {
        const int i = tid >> 3, ph = tid & 7;
        const unsigned short* src = out1 + (size_t)(b * 128 + ch0 + i) * T_;
        for (int t = ph; t < X; t += 8) {
            int g = t0g + t;
            st[0][t + 2][i] = ((unsigned)g < (unsigned)T_) ? src[g] : (unsigned short)0;
        }
    }
    __syncthreads();

    const int lane = tid & 63, wave = tid >> 6;
    const int lt = lane & 15, q = lane >> 4;
    const int i0 = (q & 1) * 8;
    const int roff1 = (q < 2) ? 0 : 2;   // MFMA#1: taps at rows t / t+2

    int cur = 0;
    for (int k = 0; k < nconv; ++k) {
        const int olo = 2 * k + 2, ohi = X - 2 * k - 2;
        const int thi = (ohi + 15) >> 4;   // tiles to compute
        const int nxt = cur ^ 1;

        short8 A1 = *(const short8*)&wL1[(k * 16 + lt) * 32 + q * 8];
        short8 A2 = (q < 2)
            ? *(const short8*)&wL2[(k * 16 + lt) * 16 + q * 8]
            : *(const short8*)&zb[i0];
        float4 pp[4];
#pragma unroll
        for (int r = 0; r < 4; ++r)
            pp[r] = *(const float4*)&pL[k * 16 + 4 * q + r][0];

        for (int tt = wave; tt < thi; tt += 2) {
            const int t = tt * 16 + lt;
            f32x4 acc = {0.f, 0.f, 0.f, 0.f};
            short8 B1 = *(const short8*)&st[cur][t + roff1][i0];
            acc = __builtin_amdgcn_mfma_f32_16x16x32_bf16(A1, B1, acc, 0, 0, 0);
            short8 B2 = *(const short8*)&st[cur][t + 4][i0];
            acc = __builtin_amdgcn_mfma_f32_16x16x32_bf16(A2, B2, acc, 0, 0, 0);

            const int g = t0g + t;
            const bool ok = (t >= olo) && (t < ohi) && ((unsigned)g < (unsigned)T_);
            ushort4v o4;
#pragma unroll
            for (int r = 0; r < 4; ++r) {
                float v = fmaxf(acc[r] + pp[r].x, 0.f) * pp[r].y + pp[r].z;
                unsigned short h = f2bf(v);
                o4[r] = ok ? h : (unsigned short)0;
            }
            *(ushort4v*)&st[nxt][t + 2][4 * q] = o4;
        }
        __syncthreads();

        // store central TI columns of new state to chainout (bf16)
        {
            const int j = j0 + k;
            const int pair = j * (j + 3) / 2 + c;
            unsigned short* dst = chainout + ((size_t)(pair * B_ + b) * 16) * T_
                                + tile * TI;
            const int i = tid >> 3, ph = tid & 7;
            for (int t2 = ph; t2 < TI; t2 += 8)
                dst[i * T_ + t2] = st[nxt][halo + t2 + 2][i];
        }
        cur = nxt;
    }
}

// ---------------------------------------------------------------------------
// Elementwise tail with fused SE excitation:
//   s2 = sigmoid(W2 relu(W1 (ssum/T) + b1) + b2)   (computed per-wg)
//   y = out3*s2 + residual; sp = obn(relu(y)); store sp;
//   pooled[b, chOff+c] = mean_t relu(fbn(sp)).
template<bool HAS_R2>
__global__ __launch_bounds__(256) void fuse_kernel(
    const float* __restrict__ out3, const float* __restrict__ ssum,
    const float* __restrict__ w1se, const float* __restrict__ b1se,
    const float* __restrict__ w2se, const float* __restrict__ b2se,
    const float* __restrict__ res0, int r0s,
    const float* __restrict__ res1,
    const float* __restrict__ obnp, const float* __restrict__ fbnp, int chOff,
    float* __restrict__ spOut, float* __restrict__ pooled)
{
    __shared__ float sL[128], red[128], hL[16];
    const int tid = threadIdx.x;
    const int row = blockIdx.x * 4 + (tid >> 6);
    const int lane = tid & 63;
    const int b = row >> 7, c = row & 127;   // b uniform per wg (4 rows/wg)

    // SE MLP (redundant per wg; ~2K FMA)
    if (tid < 128) sL[tid] = ssum[b * 128 + tid] * (1.f / 600.f);
    __syncthreads();
    if (tid < 128) {
        int h = tid >> 3, part = tid & 7;
        float a = 0.f;
        const float* wrow = w1se + h * 128 + part * 16;
#pragma unroll
        for (int k = 0; k < 16; ++k) a += wrow[k] * sL[part * 16 + k];
        red[tid] = a;
    }
    __syncthreads();
    if (tid < 16) {
        float a = b1se[tid];
#pragma unroll
        for (int p = 0; p < 8; ++p) a += red[tid * 8 + p];
        hL[tid] = fmaxf(a, 0.f);
    }
    __syncthreads();
    float a2 = b2se[c];
#pragma unroll
    for (int qq = 0; qq < 16; ++qq) a2 += w2se[c * 16 + qq] * hL[qq];
    const float s2v = 1.f / (1.f + expf(-a2));

    float g = obnp[c], bb = obnp[128 + c], m = obnp[256 + c], v = obnp[384 + c];
    float osc = g * rsqrtf(v + 1e-5f), osh = bb - m * osc;
    int fc = chOff + c;
    float fg = fbnp[fc], fb2 = fbnp[1024 + fc], fm = fbnp[2048 + fc], fv = fbnp[3072 + fc];
    float fsc = fg * rsqrtf(fv + 1e-5f), fsh = fb2 - fm * fsc;
    int base = (b * 128 + c) * T_;
    float psum = 0.f;
    for (int t = lane; t < T_; t += 64) {
        float o3 = out3[base + t];
        float r = res0[b * r0s + c * T_ + t];
        if (HAS_R2) r += res1[b * 614400 + c * T_ + t];
        float fin = o3 * s2v + r;
        float sp = fmaxf(fin, 0.f) * osc + osh;
        spOut[base + t] = sp;
        psum += fmaxf(sp * fsc + fsh, 0.f);
    }
    for (int mo = 32; mo > 0; mo >>= 1) psum += __shfl_xor(psum, mo);
    if (lane == 0) pooled[b * 1024 + fc] = psum * (1.f / 600.f);
}

// pooled tail for x channels 896..1023
__global__ __launch_bounds__(256) void pooledx_kernel(
    const float* __restrict__ x, const float* __restrict__ fbnp,
    float* __restrict__ pooled)
{
    const int tid = threadIdx.x;
    const int row = blockIdx.x * 4 + (tid >> 6);
    const int lane = tid & 63;
    const int b = row >> 7, c = row & 127;
    int fc = 896 + c;
    float fg = fbnp[fc], fb2 = fbnp[1024 + fc], fm = fbnp[2048 + fc], fv = fbnp[3072 + fc];
    float fsc = fg * rsqrtf(fv + 1e-5f), fsh = fb2 - fm * fsc;
    int base = (b * 1024 + fc) * T_;
    float psum = 0.f;
    for (int t = lane; t < T_; t += 64)
        psum += fmaxf(x[base + t] * fsc + fsh, 0.f);
    for (int mo = 32; mo > 0; mo >>= 1) psum += __shfl_xor(psum, mo);
    if (lane == 0) pooled[b * 1024 + fc] = psum * (1.f / 600.f);
}

// final classifier
__global__ __launch_bounds__(256) void logits_kernel(
    const float* __restrict__ pooled, const float* __restrict__ fcw,
    const float* __restrict__ fcb, float* __restrict__ outp)
{
    __shared__ float red[256];
    const int tid = threadIdx.x;
    const int item = tid & 63, part = tid >> 6;
    const int b = item >> 1, cls = item & 1;
    float a = 0.f;
    for (int c = part * 256; c < part * 256 + 256; ++c)
        a += pooled[b * 1024 + c] * fcw[cls * 1024 + c];
    red[tid] = a;
    __syncthreads();
    if (tid < 64)
        outp[b * 2 + cls] = red[tid] + red[tid + 64] + red[tid + 128] + red[tid + 192] + fcb[cls];
}

// ---------------------------------------------------------------------------
extern "C" void kernel_launch(void* const* d_in, const int* in_sizes, int n_in,
                              void* d_out, int out_size, void* d_ws, size_t ws_size,
                              hipStream_t stream) {
    const float* x    = (const float*)d_in[0];
    const float* w1   = (const float*)d_in[1];
    const float* b1   = (const float*)d_in[2];
    const float* bn1  = (const float*)d_in[3];
    const float* cw   = (const float*)d_in[4];
    const float* cb   = (const float*)d_in[5];
    const float* ibn  = (const float*)d_in[6];
    const float* w3   = (const float*)d_in[7];
    const float* b3   = (const float*)d_in[8];
    const float* bn3  = (const float*)d_in[9];
    const float* se1w = (const float*)d_in[10];
    const float* se1b = (const float*)d_in[11];
    const float* se2w = (const float*)d_in[12];
    const float* se2b = (const float*)d_in[13];
    const float* obn  = (const float*)d_in[14];
    const float* fbn  = (const float*)d_in[15];
    const float* fcw  = (const float*)d_in[16];
    const float* fcb  = (const float*)d_in[17];
    const float* wsp[7] = {(const float*)d_in[18], (const float*)d_in[19],
                           (const float*)d_in[20], (const float*)d_in[21],
                           (const float*)d_in[22], (const float*)d_in[23],
                           (const float*)d_in[24]};

    float* ws = (float*)d_ws;
    const int NT = 128 * T_ * B_;          // 2,457,600 per (B,128,T) tensor
    unsigned short* out1h = (unsigned short*)ws;   // bf16, in NT-float region
    float* out3   = ws + NT;
    float* spA    = out3 + NT;
    float* spB    = spA + NT;
    float* sbuf   = spB + NT;              // 7*4096
    float* pooled = sbuf + 7 * 4096;       // 32768
    unsigned short* chainout = (unsigned short*)(pooled + 32768); // 35*32*9600

    pooledx_kernel<<<1024, 256, 0, stream>>>(x, fbn, pooled);

    dim3 gGrid(10, B_);        // ceil(600/64) x B
    dim3 iGrid(12, 8, B_);     // t-tiles x chains x B

    float* spBufs[2] = {spA, spB};
    for (int i = 0; i < 7; ++i) {
        float* spOut = spBufs[i & 1];
        const float* spIn = spBufs[(i & 1) ^ 1];

        if (i == 0)
            gemm_kernel<false><<<gGrid, 256, 0, stream>>>(
                x, 614400, nullptr, w1, b1, bn1, out1h, sbuf + i * 4096);
        else
            gemm_kernel<true><<<gGrid, 256, 0, stream>>>(
                spIn, 76800, x + i * 76800,
                w1 + i * 16384, b1 + i * 128, bn1 + i * 512, out1h,
                sbuf + i * 4096);

        inner_kernel<<<iGrid, 128, 0, stream>>>(
            out1h, chainout, cw + i * 5376, cb + i * 112, ibn + i * 448);

        gemm3_kernel<<<gGrid, 256, 0, stream>>>(
            chainout, out1h,
            w3 + i * 16384, b3 + i * 128, bn3 + i * 512, out3, sbuf + i * 4096,
            wsp[0] + 2 * i, wsp[1] + 3 * i, wsp[2] + 4 * i, wsp[3] + 5 * i,
            wsp[4] + 6 * i, wsp[5] + 7 * i, wsp[6] + 8 * i);

        if (i == 0)
            fuse_kernel<false><<<1024, 256, 0, stream>>>(
                out3, sbuf + i * 4096, se1w, se1b, se2w, se2b,
                x, 614400, nullptr, obn, fbn, 0, spOut, pooled);
        else
            fuse_kernel<true><<<1024, 256, 0, stream>>>(
                out3, sbuf + i * 4096,
                se1w + i * 2048, se1b + i * 16, se2w + i * 2048, se2b + i * 128,
                spIn, 76800, x + i * 76800,
                obn + i * 512, fbn, i * 128, spOut, pooled);
    }

    logits_kernel<<<1, 256, 0, stream>>>(pooled, fcw, fcb, (float*)d_out);
}